// Round 2
// baseline (186.233 us; speedup 1.0000x reference)
//
#include <hip/hip_runtime.h>

// Q=32, S=25, L=64, F=256, H=64
// out[q,s,i,f] = sum_j softmax_j( sum_h tanh(Wq[q,i,h]*Wh[s,j,h]) ) * hs[s,j,f]
// Wq = (qs @ W^T + b) * 2*log2(e)   (pre-scaled so exp2 arg is ready)
// Wh =  hs @ W^T + b
// tanh(x) = 1 - 2/(1+exp2(2*log2e*x)); constant 64 per score row drops under softmax.
// 4 h-terms share one v_rcp:  sum 1/(1+e_k) = N/D  (clamped e<=2^18 -> no overflow)

#define NQ 32
#define NS 25
#define NL 64
#define NF 256
#define NH 64

#define K2LOG2E 2.8853900817779268f
#define C_LOG2E 1.4426950408889634f

#define SCS 65      // Sc row stride (odd -> conflict-free scalar access)
#define HSS 260     // staged hs chunk row stride (float4-aligned, +4 pad)
#define B_OFF 2048  // Blds offset in floats
#define HS_OFF 2240 // hs chunk offset in floats (Sc occupies [0,2080))
#define SMEM_FLOATS 6400  // 25.6 KB -> 6 blocks/CU by LDS

// ---------------- projection kernel ----------------
// One thread per (row,h): 3648 rows x 64 h; 4 rows/block, 912 blocks.
// Register-light on purpose (round-1 proj suspected of VGPR spills).
__global__ __launch_bounds__(256) void proj_kernel(
    const float* __restrict__ qs, const float* __restrict__ hs,
    const float* __restrict__ W, const float* __restrict__ b,
    float* __restrict__ Wqs, float* __restrict__ Whs)
{
    const int t = threadIdx.x;
    const int h = t & 63;
    const int r = blockIdx.x * 4 + (t >> 6);
    const bool is_q = (r < 2048);
    const float* row = is_q ? (qs + (size_t)r * NF) : (hs + (size_t)(r - 2048) * NF);
    const float4* x4 = (const float4*)row;          // broadcast across 64 lanes
    const float4* w4 = (const float4*)(W + h * NF); // per-lane row stream (L1/L2 hot)
    float acc = 0.f;
#pragma unroll 4
    for (int k = 0; k < NF / 4; ++k) {
        float4 x = x4[k], w = w4[k];
        acc += x.x * w.x + x.y * w.y + x.z * w.z + x.w * w.w;
    }
    acc += b[h];
    if (is_q) acc *= K2LOG2E;
    const int rr = is_q ? r : (r - 2048);
    float* dst = is_q ? Wqs : Whs;
    dst[(size_t)rr * NH + h] = acc;  // lanes h consecutive -> coalesced
}

// ---------------- fused attention kernel ----------------
// Grid 1600: (q, s, half). Block handles 32 i-rows x 64 j. 256 threads.
// LDS: scores phase  A[32x64] @0 (swizzled), B[64x64] @B_OFF (swizzled)
//      PV phase      Sc[32x65] @0,  hs chunk [16x260] @HS_OFF
__global__ __launch_bounds__(256, 5) void attn_kernel(
    const float* __restrict__ Wqs, const float* __restrict__ Whs,
    const float* __restrict__ hs, float* __restrict__ out)
{
    __shared__ float smem[SMEM_FLOATS];
    const int t = threadIdx.x;
    const int bid = blockIdx.x;
    const int half = bid & 1;
    const int s = (bid >> 1) % NS;
    const int q = bid / (2 * NS);

    // ---- stage A (32x64) and B (64x64), float4-XOR-swizzled rows ----
    {
        const float4* a4 = (const float4*)(Wqs + ((size_t)q * NL + half * 32) * NH);
        const float4* b4 = (const float4*)(Whs + (size_t)s * NL * NH);
#pragma unroll
        for (int u = 0; u < 2; ++u) {        // A: 512 float4
            int idx = t + 256 * u;
            int i = idx >> 4, g = idx & 15;
            *(float4*)&smem[i * 64 + 4 * (g ^ (i & 15))] = a4[idx];
        }
#pragma unroll
        for (int u = 0; u < 4; ++u) {        // B: 1024 float4
            int idx = t + 256 * u;
            int j = idx >> 4, g = idx & 15;
            *(float4*)&smem[B_OFF + j * 64 + 4 * (g ^ (j & 15))] = b4[idx];
        }
    }
    __syncthreads();

    // ---- scores: 2x4 tile per thread, quad-combined rcp over 4 h-steps ----
    const int i0 = (t >> 4) * 2;   // 0..30
    const int j0 = (t & 15) * 4;   // 0..60
    float sum[2][4] = {{0.f, 0.f, 0.f, 0.f}, {0.f, 0.f, 0.f, 0.f}};

#pragma unroll 2
    for (int h4 = 0; h4 < 16; ++h4) {
        float4 av[2], bv[4];
#pragma unroll
        for (int ii = 0; ii < 2; ++ii)
            av[ii] = *(const float4*)&smem[(i0 + ii) * 64 + 4 * (h4 ^ ((i0 + ii) & 15))];
#pragma unroll
        for (int jj = 0; jj < 4; ++jj)
            bv[jj] = *(const float4*)&smem[B_OFF + (j0 + jj) * 64 + 4 * (h4 ^ ((j0 + jj) & 15))];
#pragma unroll
        for (int ii = 0; ii < 2; ++ii) {
#pragma unroll
            for (int jj = 0; jj < 4; ++jj) {
                float e0 = __builtin_amdgcn_exp2f(fminf(av[ii].x * bv[jj].x, 18.f));
                float e1 = __builtin_amdgcn_exp2f(fminf(av[ii].y * bv[jj].y, 18.f));
                float e2 = __builtin_amdgcn_exp2f(fminf(av[ii].z * bv[jj].z, 18.f));
                float e3 = __builtin_amdgcn_exp2f(fminf(av[ii].w * bv[jj].w, 18.f));
                float s01 = e0 + e1, s23 = e2 + e3;
                float n01 = s01 + 2.f, n23 = s23 + 2.f;
                float d01 = fmaf(e0, e1, s01) + 1.f;
                float d23 = fmaf(e2, e3, s23) + 1.f;
                float num = fmaf(n01, d23, n23 * d01);
                float den = d01 * d23;
                sum[ii][jj] = fmaf(num, __builtin_amdgcn_rcpf(den), sum[ii][jj]);
            }
        }
    }
    __syncthreads();  // done reading A/B; Sc overlaps A region

    // score (shifted) = -2 * sum
#pragma unroll
    for (int ii = 0; ii < 2; ++ii)
#pragma unroll
        for (int jj = 0; jj < 4; ++jj)
            smem[(i0 + ii) * SCS + (j0 + jj)] = -2.f * sum[ii][jj];
    __syncthreads();

    // ---- softmax over j: 8 threads/row, 8 j each ----
    {
        const int i = t >> 3, c = t & 7;
        float* row = &smem[i * SCS + c * 8];
        float v[8];
        float m = -1e30f;
#pragma unroll
        for (int k = 0; k < 8; ++k) { v[k] = row[k]; m = fmaxf(m, v[k]); }
        m = fmaxf(m, __shfl_xor(m, 1));
        m = fmaxf(m, __shfl_xor(m, 2));
        m = fmaxf(m, __shfl_xor(m, 4));
        float d = 0.f;
#pragma unroll
        for (int k = 0; k < 8; ++k) {
            float p = __builtin_amdgcn_exp2f((v[k] - m) * C_LOG2E);
            v[k] = p; d += p;
        }
        d += __shfl_xor(d, 1);
        d += __shfl_xor(d, 2);
        d += __shfl_xor(d, 4);
        const float inv = __builtin_amdgcn_rcpf(d);
#pragma unroll
        for (int k = 0; k < 8; ++k) row[k] = v[k] * inv;
    }
    __syncthreads();

    // ---- PV: out[i][f] = sum_j att[i][j]*hs[s][j][f], j in 4 chunks of 16 ----
    const int c  = t & 15;      // f-group: f = 4c + 64k
    const int ig = t >> 4;      // rows ig, ig+16
    const int w  = t >> 6;      // wave id
    const int lane = t & 63;
    const float* hsS = hs + (size_t)s * NL * NF;

    float4 acc[2][4];
#pragma unroll
    for (int m = 0; m < 2; ++m)
#pragma unroll
        for (int k = 0; k < 4; ++k) acc[m][k] = make_float4(0.f, 0.f, 0.f, 0.f);

    for (int ch = 0; ch < 4; ++ch) {
        // stage 16 hs rows via async global->LDS (wave-uniform base + lane*16)
#pragma unroll
        for (int u = 0; u < 4; ++u) {
            const int jl = u * 4 + w;
            const float* gp = hsS + (size_t)(ch * 16 + jl) * NF + lane * 4;
            __builtin_amdgcn_global_load_lds(
                (const __attribute__((address_space(1))) unsigned int*)gp,
                (__attribute__((address_space(3))) unsigned int*)&smem[HS_OFF + jl * HSS],
                16, 0, 0);
        }
        asm volatile("s_waitcnt vmcnt(0)" ::: "memory");
        __syncthreads();

#pragma unroll 4
        for (int jl = 0; jl < 16; ++jl) {
            const int jg = ch * 16 + jl;
            const float p0 = smem[ig * SCS + jg];
            const float p1 = smem[(ig + 16) * SCS + jg];
            const float* hrow = &smem[HS_OFF + jl * HSS + 4 * c];
#pragma unroll
            for (int k = 0; k < 4; ++k) {
                float4 hv = *(const float4*)(hrow + 64 * k);
                acc[0][k].x = fmaf(p0, hv.x, acc[0][k].x);
                acc[0][k].y = fmaf(p0, hv.y, acc[0][k].y);
                acc[0][k].z = fmaf(p0, hv.z, acc[0][k].z);
                acc[0][k].w = fmaf(p0, hv.w, acc[0][k].w);
                acc[1][k].x = fmaf(p1, hv.x, acc[1][k].x);
                acc[1][k].y = fmaf(p1, hv.y, acc[1][k].y);
                acc[1][k].z = fmaf(p1, hv.z, acc[1][k].z);
                acc[1][k].w = fmaf(p1, hv.w, acc[1][k].w);
            }
        }
        __syncthreads();  // all waves done reading before next chunk overwrites
    }

    // ---- write out: rows {ig, ig+16} of this half, f = 4c + 64k ----
    const size_t obase = ((size_t)(q * NS + s) * NL + half * 32) * NF;
#pragma unroll
    for (int m = 0; m < 2; ++m) {
        float* orow = out + obase + (size_t)(ig + 16 * m) * NF + 4 * c;
#pragma unroll
        for (int k = 0; k < 4; ++k)
            *(float4*)(orow + 64 * k) = acc[m][k];
    }
}

extern "C" void kernel_launch(void* const* d_in, const int* in_sizes, int n_in,
                              void* d_out, int out_size, void* d_ws, size_t ws_size,
                              hipStream_t stream) {
    const float* qs = (const float*)d_in[0];
    const float* hs = (const float*)d_in[1];
    const float* W  = (const float*)d_in[2];
    const float* b  = (const float*)d_in[3];
    float* out = (float*)d_out;

    float* Wqs = (float*)d_ws;               // 32*64*64 floats (pre-scaled by 2log2e)
    float* Whs = Wqs + NQ * NL * NH;         // 25*64*64 floats

    proj_kernel<<<912, 256, 0, stream>>>(qs, hs, W, b, Wqs, Whs);
    attn_kernel<<<NQ * NS * 2, 256, 0, stream>>>(Wqs, Whs, hs, out);
}

// Round 4
// 128.701 us; speedup vs baseline: 1.4470x; 1.4470x over previous
//
#include <hip/hip_runtime.h>

// Q=32, S=25, L=64, F=256, H=64
// out[q,s,i,f] = sum_j softmax_j( sum_h tanh(Wq[q,i,h]*Wh[s,j,h]) ) * hs[s,j,f]
// Wq = (qs @ W^T + b) * 2*log2(e)  (pre-scaled: exp2 arg ready), Wh = hs @ W^T + b
// tanh(x) = 1 - 2/(1+exp2(2log2e*x)); the per-row constant 64 drops under softmax.
// 4 h-terms share one v_rcp (e clamped <= 2^18 so products never overflow fp32).
// PV phase uses bf16 MFMA 16x16x32 (att and hs in bf16: adds ~0.006 abs err, thr 0.092).

#define NQ 32
#define NS 25
#define NL 64
#define NF 256
#define NH 64

#define K2LOG2E 2.8853900817779268f
#define C_LOG2E 1.4426950408889634f

typedef __attribute__((ext_vector_type(8))) short bf16x8;
typedef __attribute__((ext_vector_type(4))) float f32x4;

__device__ inline unsigned short f2bf(float x) {
    union { float f; unsigned int u; } v; v.f = x;
    unsigned int r = v.u + 0x7fffu + ((v.u >> 16) & 1u);
    return (unsigned short)(r >> 16);
}

// ---------------- prep kernel: proj (blocks 0..227) + hsT transpose (228..327) ----
// proj: W staged in LDS stride 260 (conflict-free 8-lane phases for b128); x rows
// read via readfirstlane-forced scalar loads (uniform -> s_load, L1-resident).
#define WS 260
__global__ __launch_bounds__(256) void prep_kernel(
    const float* __restrict__ qs, const float* __restrict__ hs,
    const float* __restrict__ W, const float* __restrict__ b,
    float* __restrict__ Wqs, float* __restrict__ Whs,
    unsigned short* __restrict__ hsT)
{
    __shared__ float lds[64 * WS];  // 66560 B (launched fine on gfx950 in r3)
    const int t = threadIdx.x;
    const int bid = blockIdx.x;

    if (bid < 228) {
        const int r0 = bid * 16;
        const float4* W4 = (const float4*)W;
#pragma unroll
        for (int u = 0; u < 16; ++u) {
            int idx = t + 256 * u;
            int wr = idx >> 6, fq = idx & 63;
            *(float4*)&lds[wr * WS + 4 * fq] = W4[idx];
        }
        __syncthreads();

        const int h = t & 63;
        const int w = t >> 6;
        const float bias = b[h];

        const float4* xp[4];
        int rws[4];
#pragma unroll
        for (int k = 0; k < 4; ++k) {
            int r = __builtin_amdgcn_readfirstlane(r0 + w * 4 + k);  // wave-uniform -> SGPR
            rws[k] = r;
            xp[k] = (const float4*)((r < 2048) ? (qs + (size_t)r * NF)
                                               : (hs + (size_t)(r - 2048) * NF));
        }
        float acc[4] = {0.f, 0.f, 0.f, 0.f};
#pragma unroll 4
        for (int f4 = 0; f4 < 64; ++f4) {
            float4 wv = *(const float4*)&lds[h * WS + 4 * f4];
#pragma unroll
            for (int k = 0; k < 4; ++k) {
                float4 x = xp[k][f4];  // uniform (scalar) load
                acc[k] += x.x * wv.x + x.y * wv.y + x.z * wv.z + x.w * wv.w;
            }
        }
#pragma unroll
        for (int k = 0; k < 4; ++k) {
            int r = rws[k];
            float v = acc[k] + bias;
            if (r < 2048) Wqs[(size_t)r * NH + h] = v * K2LOG2E;
            else          Whs[(size_t)(r - 2048) * NH + h] = v;
        }
    } else {
        // hsT[s][f][j] bf16: transpose+convert one (s, 64-f chunk) per block
        const int b2 = bid - 228;
        const int s = b2 >> 2;
        const int f0 = (b2 & 3) * 64;
        unsigned short* T = (unsigned short*)lds;  // [f'][j], stride 72 shorts
        const float4* h4p = (const float4*)(hs + (size_t)s * NL * NF);
#pragma unroll
        for (int u = 0; u < 4; ++u) {
            int idx = t + 256 * u;
            int j = idx >> 4, fq = idx & 15;
            float4 v = h4p[j * 64 + (f0 >> 2) + fq];
            T[(4 * fq + 0) * 72 + j] = f2bf(v.x);
            T[(4 * fq + 1) * 72 + j] = f2bf(v.y);
            T[(4 * fq + 2) * 72 + j] = f2bf(v.z);
            T[(4 * fq + 3) * 72 + j] = f2bf(v.w);
        }
        __syncthreads();
        // write-out: 64 rows x 64 j = 512 uint4 (8 bf16 each). r3 BUG was here:
        // fl=idx>>2 walked 128 rows (stale LDS -> Inf/NaN bf16) and jg*16 skipped
        // half of each row. Correct decode: fl=idx>>3, jg=idx&7, offset jg*8.
#pragma unroll
        for (int u = 0; u < 2; ++u) {
            int idx = t + 256 * u;
            int fl = idx >> 3, jg = idx & 7;
            uint4 v = *(const uint4*)&T[fl * 72 + jg * 8];
            *(uint4*)&hsT[(size_t)(s * 256 + f0 + fl) * 64 + jg * 8] = v;
        }
    }
}

// ---------------- fused attention kernel ----------------
// Grid 1600: (q, s, half). Block: 32 i-rows x 64 j. 256 threads.
// LDS (bytes): A f32 [32][68] @0 (8704) | B f32 [64][68] @8704 (17408)
//   after scores: Sc f32 [32][65] overlaps A; att bf16 [32][72] @8704 (4608);
//   hsT chunk bf16 [128][72] @13312 (18432). Total 31744 B -> 5 blocks/CU.
#define AS 68
#define B_OFF 2176          // floats
#define SCS 65
#define ATT_BYTE 8704
#define HST_BYTE 13312
#define SMEMF 7936          // 31744 B

__global__ __launch_bounds__(256, 5) void attn_kernel(
    const float* __restrict__ Wqs, const float* __restrict__ Whs,
    const unsigned short* __restrict__ hsT, float* __restrict__ out)
{
    __shared__ float smem[SMEMF];
    const int t = threadIdx.x;
    const int bid = blockIdx.x;
    const int half = bid & 1;
    const int s = (bid >> 1) % NS;
    const int q = bid / (2 * NS);

    // ---- stage A (32x64) and B (64x64), row-major stride 68 ----
    {
        const float4* a4 = (const float4*)(Wqs + ((size_t)q * NL + half * 32) * NH);
        const float4* b4 = (const float4*)(Whs + (size_t)s * NL * NH);
#pragma unroll
        for (int u = 0; u < 2; ++u) {
            int idx = t + 256 * u;
            int i = idx >> 4, g = idx & 15;
            *(float4*)&smem[i * AS + 4 * g] = a4[idx];
        }
#pragma unroll
        for (int u = 0; u < 4; ++u) {
            int idx = t + 256 * u;
            int j = idx >> 4, g = idx & 15;
            *(float4*)&smem[B_OFF + j * AS + 4 * g] = b4[idx];
        }
    }
    __syncthreads();

    // ---- scores: rows {i0,i0+1}, cols {jn+16*jj}; quad-combined rcp ----
    const int i0 = (t >> 4) * 2;
    const int jn = t & 15;
    float sum[2][4] = {{0.f, 0.f, 0.f, 0.f}, {0.f, 0.f, 0.f, 0.f}};

#pragma unroll 2
    for (int h4 = 0; h4 < 16; ++h4) {
        float4 av[2], bv[4];
        av[0] = *(const float4*)&smem[i0 * AS + 4 * h4];        // broadcast
        av[1] = *(const float4*)&smem[(i0 + 1) * AS + 4 * h4];
#pragma unroll
        for (int jj = 0; jj < 4; ++jj)                          // 2-way: free
            bv[jj] = *(const float4*)&smem[B_OFF + (jn + 16 * jj) * AS + 4 * h4];
#pragma unroll
        for (int ii = 0; ii < 2; ++ii) {
#pragma unroll
            for (int jj = 0; jj < 4; ++jj) {
                float e0 = __builtin_amdgcn_exp2f(fminf(av[ii].x * bv[jj].x, 18.f));
                float e1 = __builtin_amdgcn_exp2f(fminf(av[ii].y * bv[jj].y, 18.f));
                float e2 = __builtin_amdgcn_exp2f(fminf(av[ii].z * bv[jj].z, 18.f));
                float e3 = __builtin_amdgcn_exp2f(fminf(av[ii].w * bv[jj].w, 18.f));
                float s01 = e0 + e1, s23 = e2 + e3;
                float d01 = fmaf(e0, e1, s01) + 1.f;
                float d23 = fmaf(e2, e3, s23) + 1.f;
                float num = fmaf(s01 + 2.f, d23, (s23 + 2.f) * d01);
                sum[ii][jj] = fmaf(num, __builtin_amdgcn_rcpf(d01 * d23), sum[ii][jj]);
            }
        }
    }
    __syncthreads();  // A/B dead; Sc overlaps A

#pragma unroll
    for (int ii = 0; ii < 2; ++ii)
#pragma unroll
        for (int jj = 0; jj < 4; ++jj)
            smem[(i0 + ii) * SCS + jn + 16 * jj] = -2.f * sum[ii][jj];
    __syncthreads();

    // ---- softmax over j (8 threads/row) + bf16 att into A-frag-friendly layout ----
    {
        const int i = t >> 3, c = t & 7;
        const float* row = &smem[i * SCS + c * 8];
        float v[8];
        float m = -1e30f;
#pragma unroll
        for (int k = 0; k < 8; ++k) { v[k] = row[k]; m = fmaxf(m, v[k]); }
        m = fmaxf(m, __shfl_xor(m, 1));
        m = fmaxf(m, __shfl_xor(m, 2));
        m = fmaxf(m, __shfl_xor(m, 4));
        float d = 0.f;
#pragma unroll
        for (int k = 0; k < 8; ++k) {
            float p = __builtin_amdgcn_exp2f((v[k] - m) * C_LOG2E);
            v[k] = p; d += p;
        }
        d += __shfl_xor(d, 1);
        d += __shfl_xor(d, 2);
        d += __shfl_xor(d, 4);
        const float inv = __builtin_amdgcn_rcpf(d);
        unsigned int w0 = f2bf(v[0] * inv) | ((unsigned int)f2bf(v[1] * inv) << 16);
        unsigned int w1 = f2bf(v[2] * inv) | ((unsigned int)f2bf(v[3] * inv) << 16);
        unsigned int w2 = f2bf(v[4] * inv) | ((unsigned int)f2bf(v[5] * inv) << 16);
        unsigned int w3 = f2bf(v[6] * inv) | ((unsigned int)f2bf(v[7] * inv) << 16);
        *(uint4*)((char*)smem + ATT_BYTE + i * 144 + c * 16) = make_uint4(w0, w1, w2, w3);
    }
    __syncthreads();

    // ---- PV via bf16 MFMA: [32 x 64j] @ [64j x 256f], 2 f-chunks of 128 ----
    const int lane = t & 63;
    const int wv = t >> 6;
    const int m15 = lane & 15;
    const int quad = lane >> 4;

    // A-frags (same for both chunks): A[m=lane&15][k=quad*8+j]
    bf16x8 afr[2][2];
#pragma unroll
    for (int m = 0; m < 2; ++m)
#pragma unroll
        for (int k = 0; k < 2; ++k)
            afr[m][k] = *(const bf16x8*)((const char*)smem + ATT_BYTE
                          + (m * 16 + m15) * 144 + k * 64 + quad * 16);

    const unsigned short* hsTs = hsT + (size_t)s * NF * NL;
    for (int ch = 0; ch < 2; ++ch) {
        // stage 128 f-rows (16 KB), coalesced -> stride-72 bf16 rows
#pragma unroll
        for (int u = 0; u < 4; ++u) {
            int idx = t + 256 * u;
            int fl = idx >> 3, jg = idx & 7;
            uint4 vv = *(const uint4*)(hsTs + (size_t)(ch * 128 + fl) * 64 + jg * 8);
            *(uint4*)((char*)smem + HST_BYTE + fl * 144 + jg * 16) = vv;
        }
        __syncthreads();

        f32x4 acc[2][2];
#pragma unroll
        for (int m = 0; m < 2; ++m)
#pragma unroll
            for (int n = 0; n < 2; ++n)
                acc[m][n] = (f32x4){0.f, 0.f, 0.f, 0.f};

#pragma unroll
        for (int k = 0; k < 2; ++k) {
            bf16x8 bfr[2];
#pragma unroll
            for (int n = 0; n < 2; ++n)  // B[k=quad*8+j][n=lane&15] from hsT_lds[f][j]
                bfr[n] = *(const bf16x8*)((const char*)smem + HST_BYTE
                            + (wv * 32 + n * 16 + m15) * 144 + k * 64 + quad * 16);
#pragma unroll
            for (int m = 0; m < 2; ++m)
#pragma unroll
                for (int n = 0; n < 2; ++n)
                    acc[m][n] = __builtin_amdgcn_mfma_f32_16x16x32_bf16(
                        afr[m][k], bfr[n], acc[m][n], 0, 0, 0);
        }

        // C layout: col = lane&15 (f), row = quad*4 + reg (i)
        const size_t obase = ((size_t)(q * NS + s) * NL + half * 32) * NF + ch * 128;
#pragma unroll
        for (int m = 0; m < 2; ++m)
#pragma unroll
            for (int n = 0; n < 2; ++n)
#pragma unroll
                for (int r = 0; r < 4; ++r)
                    out[obase + (size_t)(m * 16 + quad * 4 + r) * NF
                        + wv * 32 + n * 16 + m15] = acc[m][n][r];
        __syncthreads();  // before next chunk overwrites hsT_lds
    }
}

extern "C" void kernel_launch(void* const* d_in, const int* in_sizes, int n_in,
                              void* d_out, int out_size, void* d_ws, size_t ws_size,
                              hipStream_t stream) {
    const float* qs = (const float*)d_in[0];
    const float* hs = (const float*)d_in[1];
    const float* W  = (const float*)d_in[2];
    const float* b  = (const float*)d_in[3];
    float* out = (float*)d_out;

    float* Wqs = (float*)d_ws;                         // 131072 f
    float* Whs = Wqs + NQ * NL * NH;                   // 102400 f
    unsigned short* hsT = (unsigned short*)(Whs + NS * NL * NH);  // 409600 bf16

    prep_kernel<<<328, 256, 0, stream>>>(qs, hs, W, b, Wqs, Whs, hsT);
    attn_kernel<<<NQ * NS * 2, 256, 0, stream>>>(Wqs, Whs, hsT, out);
}

// Round 5
// 122.552 us; speedup vs baseline: 1.5196x; 1.0502x over previous
//
#include <hip/hip_runtime.h>

// Q=32, S=25, L=64, F=256, H=64
// out[q,s,i,f] = sum_j softmax_j( sum_h tanh(Wq[q,i,h]*Wh[s,j,h]) ) * hs[s,j,f]
// Wq = (qs @ W^T + b) * 2*log2(e)  (pre-scaled: exp2 arg ready), Wh = hs @ W^T + b
// tanh(x) = 1 - 2/(1+exp2(2log2e*x)); per-row constant 64 drops under softmax.
// 4 h-terms share one v_rcp (e clamped <= 2^18: products never overflow fp32).
// proj runs as bf16 MFMA GEMM with hi/lo split (~2^-16 rel err); PV via bf16 MFMA
// with B-frags read directly from L2-hot hsT (no LDS staging, no chunk barriers).

#define NQ 32
#define NS 25
#define NL 64
#define NF 256
#define NH 64

#define K2LOG2E 2.8853900817779268f
#define C_LOG2E 1.4426950408889634f

typedef __attribute__((ext_vector_type(8))) short bf16x8;
typedef __attribute__((ext_vector_type(4))) float f32x4;

__device__ inline unsigned short f2bf(float x) {  // RNE
    union { float f; unsigned int u; } v; v.f = x;
    unsigned int r = v.u + 0x7fffu + ((v.u >> 16) & 1u);
    return (unsigned short)(r >> 16);
}

// split 8 fp32 into hi/lo bf16 (truncation both: residual ~2^-16 rel, fine since
// the lo*whi / hi*wlo MFMA terms recover it)
__device__ inline void cvt_hilo(float4 a, float4 b, bf16x8* hi, bf16x8* lo) {
    float x[8] = {a.x, a.y, a.z, a.w, b.x, b.y, b.z, b.w};
    bf16x8 h8, l8;
#pragma unroll
    for (int i = 0; i < 8; ++i) {
        union { float f; unsigned int u; } v; v.f = x[i];
        unsigned short hh = (unsigned short)(v.u >> 16);
        h8[i] = (short)hh;
        union { unsigned int u; float f; } hf; hf.u = (unsigned int)hh << 16;
        union { float f; unsigned int u; } rv; rv.f = x[i] - hf.f;
        l8[i] = (short)(unsigned short)(rv.u >> 16);
    }
    *hi = h8; *lo = l8;
}

// ---------------- prep kernel ----------------
// bid 0..113: proj as MFMA GEMM. Block = 32 rows; wave w: m-tile (w&1)*16,
//   h-half (w>>1)*32 (2 n-tiles). A/B frags direct from global fp32 -> hi/lo.
// bid 114..213: hsT[s][f][j] bf16 transpose (one (s, 64-f chunk) per block).
#define PROJ_BLOCKS 114
__global__ __launch_bounds__(256) void prep_kernel(
    const float* __restrict__ qs, const float* __restrict__ hs,
    const float* __restrict__ W, const float* __restrict__ b,
    float* __restrict__ Wqs, float* __restrict__ Whs,
    unsigned short* __restrict__ hsT)
{
    __shared__ unsigned short T[64 * 72];  // hsT path only (9216 B)
    const int t = threadIdx.x;
    const int bid = blockIdx.x;

    if (bid < PROJ_BLOCKS) {
        const int w = t >> 6, lane = t & 63;
        const int m15 = lane & 15, quad = lane >> 4;
        const int r0 = bid * 32 + (w & 1) * 16;   // m-tile base (16-aligned: never
        const int h0 = (w >> 1) * 32;             //  straddles the 2048 qs/hs split)
        const bool is_q = (r0 < 2048);
        const float* Xrow = is_q ? (qs + (size_t)(r0 + m15) * NF)
                                 : (hs + (size_t)(r0 - 2048 + m15) * NF);
        f32x4 acc[2] = {(f32x4){0.f,0.f,0.f,0.f}, (f32x4){0.f,0.f,0.f,0.f}};

#pragma unroll 2
        for (int kk = 0; kk < 8; ++kk) {
            const int f0 = kk * 32 + quad * 8;
            bf16x8 xhi, xlo;
            cvt_hilo(*(const float4*)(Xrow + f0), *(const float4*)(Xrow + f0 + 4),
                     &xhi, &xlo);
#pragma unroll
            for (int nt = 0; nt < 2; ++nt) {
                const float* Wrow = W + (size_t)(h0 + nt * 16 + m15) * NF + f0;
                bf16x8 whi, wlo;
                cvt_hilo(*(const float4*)(Wrow), *(const float4*)(Wrow + 4),
                         &whi, &wlo);
                acc[nt] = __builtin_amdgcn_mfma_f32_16x16x32_bf16(xhi, whi, acc[nt], 0, 0, 0);
                acc[nt] = __builtin_amdgcn_mfma_f32_16x16x32_bf16(xhi, wlo, acc[nt], 0, 0, 0);
                acc[nt] = __builtin_amdgcn_mfma_f32_16x16x32_bf16(xlo, whi, acc[nt], 0, 0, 0);
            }
        }
        // C layout: col(h) = lane&15, row = quad*4 + reg
#pragma unroll
        for (int nt = 0; nt < 2; ++nt) {
            const int h = h0 + nt * 16 + m15;
            const float bias = b[h];
#pragma unroll
            for (int r = 0; r < 4; ++r) {
                const int row = r0 + quad * 4 + r;
                const float v = acc[nt][r] + bias;
                if (is_q) Wqs[(size_t)row * NH + h] = v * K2LOG2E;
                else      Whs[(size_t)(row - 2048) * NH + h] = v;
            }
        }
    } else {
        const int b2 = bid - PROJ_BLOCKS;
        const int s = b2 >> 2;
        const int f0 = (b2 & 3) * 64;
        const float4* h4p = (const float4*)(hs + (size_t)s * NL * NF);
#pragma unroll
        for (int u = 0; u < 4; ++u) {
            int idx = t + 256 * u;
            int j = idx >> 4, fq = idx & 15;
            float4 v = h4p[j * 64 + (f0 >> 2) + fq];
            T[(4 * fq + 0) * 72 + j] = f2bf(v.x);
            T[(4 * fq + 1) * 72 + j] = f2bf(v.y);
            T[(4 * fq + 2) * 72 + j] = f2bf(v.z);
            T[(4 * fq + 3) * 72 + j] = f2bf(v.w);
        }
        __syncthreads();
#pragma unroll
        for (int u = 0; u < 2; ++u) {
            int idx = t + 256 * u;
            int fl = idx >> 3, jg = idx & 7;
            uint4 v = *(const uint4*)&T[fl * 72 + jg * 8];
            *(uint4*)&hsT[(size_t)(s * 256 + f0 + fl) * 64 + jg * 8] = v;
        }
    }
}

// ---------------- fused attention kernel ----------------
// Grid 1600: (q, s, half). Block: 32 i-rows x 64 j. 256 threads.
// LDS: scores  A f32 [32][68] @0 | B f32 [64][68] @8704B  (26112 B total -> 6 blk/CU)
//      after   Sc f32 [32][65] overlaps A; att bf16 [32][72] @8704B (over dead B)
// PV B-frags come straight from global hsT (L2-hot) -> no staging, no chunk syncs.
#define AS 68
#define B_OFF 2176          // floats
#define SCS 65
#define ATT_BYTE 8704
#define SMEMF 6528          // 26112 B

__global__ __launch_bounds__(256, 6) void attn_kernel(
    const float* __restrict__ Wqs, const float* __restrict__ Whs,
    const unsigned short* __restrict__ hsT, float* __restrict__ out)
{
    __shared__ float smem[SMEMF];
    const int t = threadIdx.x;
    const int bid = blockIdx.x;
    const int half = bid & 1;
    const int s = (bid >> 1) % NS;
    const int q = bid / (2 * NS);

    // ---- stage A (32x64) and B (64x64), row-major stride 68 ----
    {
        const float4* a4 = (const float4*)(Wqs + ((size_t)q * NL + half * 32) * NH);
        const float4* b4 = (const float4*)(Whs + (size_t)s * NL * NH);
#pragma unroll
        for (int u = 0; u < 2; ++u) {
            int idx = t + 256 * u;
            int i = idx >> 4, g = idx & 15;
            *(float4*)&smem[i * AS + 4 * g] = a4[idx];
        }
#pragma unroll
        for (int u = 0; u < 4; ++u) {
            int idx = t + 256 * u;
            int j = idx >> 4, g = idx & 15;
            *(float4*)&smem[B_OFF + j * AS + 4 * g] = b4[idx];
        }
    }
    __syncthreads();

    // ---- scores: rows {i0,i0+1}, cols {jn+16*jj}; quad-combined rcp ----
    const int i0 = (t >> 4) * 2;
    const int jn = t & 15;
    float sum[2][4] = {{0.f, 0.f, 0.f, 0.f}, {0.f, 0.f, 0.f, 0.f}};

#pragma unroll 2
    for (int h4 = 0; h4 < 16; ++h4) {
        float4 av[2], bv[4];
        av[0] = *(const float4*)&smem[i0 * AS + 4 * h4];
        av[1] = *(const float4*)&smem[(i0 + 1) * AS + 4 * h4];
#pragma unroll
        for (int jj = 0; jj < 4; ++jj)
            bv[jj] = *(const float4*)&smem[B_OFF + (jn + 16 * jj) * AS + 4 * h4];
#pragma unroll
        for (int ii = 0; ii < 2; ++ii) {
#pragma unroll
            for (int jj = 0; jj < 4; ++jj) {
                float e0 = __builtin_amdgcn_exp2f(fminf(av[ii].x * bv[jj].x, 18.f));
                float e1 = __builtin_amdgcn_exp2f(fminf(av[ii].y * bv[jj].y, 18.f));
                float e2 = __builtin_amdgcn_exp2f(fminf(av[ii].z * bv[jj].z, 18.f));
                float e3 = __builtin_amdgcn_exp2f(fminf(av[ii].w * bv[jj].w, 18.f));
                float s01 = e0 + e1, s23 = e2 + e3;
                float d01 = fmaf(e0, e1, s01) + 1.f;
                float d23 = fmaf(e2, e3, s23) + 1.f;
                float num = fmaf(s01 + 2.f, d23, (s23 + 2.f) * d01);
                sum[ii][jj] = fmaf(num, __builtin_amdgcn_rcpf(d01 * d23), sum[ii][jj]);
            }
        }
    }
    __syncthreads();  // A/B dead; Sc overlaps A

#pragma unroll
    for (int ii = 0; ii < 2; ++ii)
#pragma unroll
        for (int jj = 0; jj < 4; ++jj)
            smem[(i0 + ii) * SCS + jn + 16 * jj] = -2.f * sum[ii][jj];
    __syncthreads();

    // ---- softmax over j (8 threads/row) + bf16 att in A-frag layout ----
    {
        const int i = t >> 3, c = t & 7;
        const float* row = &smem[i * SCS + c * 8];
        float v[8];
        float m = -1e30f;
#pragma unroll
        for (int k = 0; k < 8; ++k) { v[k] = row[k]; m = fmaxf(m, v[k]); }
        m = fmaxf(m, __shfl_xor(m, 1));
        m = fmaxf(m, __shfl_xor(m, 2));
        m = fmaxf(m, __shfl_xor(m, 4));
        float d = 0.f;
#pragma unroll
        for (int k = 0; k < 8; ++k) {
            float p = __builtin_amdgcn_exp2f((v[k] - m) * C_LOG2E);
            v[k] = p; d += p;
        }
        d += __shfl_xor(d, 1);
        d += __shfl_xor(d, 2);
        d += __shfl_xor(d, 4);
        const float inv = __builtin_amdgcn_rcpf(d);
        unsigned int w0 = f2bf(v[0] * inv) | ((unsigned int)f2bf(v[1] * inv) << 16);
        unsigned int w1 = f2bf(v[2] * inv) | ((unsigned int)f2bf(v[3] * inv) << 16);
        unsigned int w2 = f2bf(v[4] * inv) | ((unsigned int)f2bf(v[5] * inv) << 16);
        unsigned int w3 = f2bf(v[6] * inv) | ((unsigned int)f2bf(v[7] * inv) << 16);
        *(uint4*)((char*)smem + ATT_BYTE + i * 144 + c * 16) = make_uint4(w0, w1, w2, w3);
    }
    __syncthreads();

    // ---- PV via bf16 MFMA: [32 x 64j] @ [64j x 256f]; wave wv covers f-tiles
    //      wv*4..wv*4+3; B-frags direct from global hsT[s][f][j] (16B runs) ----
    const int lane = t & 63;
    const int wv = t >> 6;
    const int m15 = lane & 15;
    const int quad = lane >> 4;

    bf16x8 afr[2][2];  // A[m=lane&15][k=quad*8+j]
#pragma unroll
    for (int m = 0; m < 2; ++m)
#pragma unroll
        for (int k = 0; k < 2; ++k)
            afr[m][k] = *(const bf16x8*)((const char*)smem + ATT_BYTE
                          + (m * 16 + m15) * 144 + k * 64 + quad * 16);

    const unsigned short* hsTs = hsT + (size_t)s * NF * NL;
    f32x4 acc[2][4];
#pragma unroll
    for (int m = 0; m < 2; ++m)
#pragma unroll
        for (int n = 0; n < 4; ++n) acc[m][n] = (f32x4){0.f, 0.f, 0.f, 0.f};

#pragma unroll
    for (int k = 0; k < 2; ++k) {
        bf16x8 bfr[4];  // B[k=quad*8+j][n=lane&15]: row f, 8 consecutive j
#pragma unroll
        for (int n = 0; n < 4; ++n)
            bfr[n] = *(const bf16x8*)(hsTs
                        + (size_t)((wv * 4 + n) * 16 + m15) * 64 + k * 32 + quad * 8);
#pragma unroll
        for (int m = 0; m < 2; ++m)
#pragma unroll
            for (int n = 0; n < 4; ++n)
                acc[m][n] = __builtin_amdgcn_mfma_f32_16x16x32_bf16(
                    afr[m][k], bfr[n], acc[m][n], 0, 0, 0);
    }

    // C layout: col(f) = lane&15, row(i) = quad*4 + reg
    const size_t obase = ((size_t)(q * NS + s) * NL + half * 32) * NF;
#pragma unroll
    for (int m = 0; m < 2; ++m)
#pragma unroll
        for (int n = 0; n < 4; ++n)
#pragma unroll
            for (int r = 0; r < 4; ++r)
                out[obase + (size_t)(m * 16 + quad * 4 + r) * NF
                    + (wv * 4 + n) * 16 + m15] = acc[m][n][r];
}

extern "C" void kernel_launch(void* const* d_in, const int* in_sizes, int n_in,
                              void* d_out, int out_size, void* d_ws, size_t ws_size,
                              hipStream_t stream) {
    const float* qs = (const float*)d_in[0];
    const float* hs = (const float*)d_in[1];
    const float* W  = (const float*)d_in[2];
    const float* b  = (const float*)d_in[3];
    float* out = (float*)d_out;

    float* Wqs = (float*)d_ws;                         // 131072 f
    float* Whs = Wqs + NQ * NL * NH;                   // 102400 f
    unsigned short* hsT = (unsigned short*)(Whs + NS * NL * NH);  // 409600 bf16

    prep_kernel<<<PROJ_BLOCKS + NS * 4, 256, 0, stream>>>(qs, hs, W, b, Wqs, Whs, hsT);
    attn_kernel<<<NQ * NS * 2, 256, 0, stream>>>(Wqs, Whs, hsT, out);
}

// Round 6
// 119.501 us; speedup vs baseline: 1.5584x; 1.0255x over previous
//
#include <hip/hip_runtime.h>

// Q=32, S=25, L=64, F=256, H=64
// out[q,s,i,f] = sum_j softmax_j( sum_h tanh(Wq[q,i,h]*Wh[s,j,h]) ) * hs[s,j,f]
// Wq = (qs @ W^T + b) * 2*log2(e)  (pre-scaled: exp2 arg ready), Wh = hs @ W^T + b
// tanh(x) = 1 - 2/(1+exp2(2log2e*x)); per-row constant 64 drops under softmax.
// 4 h-terms share one v_rcp (e clamped <= 2^18: products never overflow fp32).
// NOTE (r5 post-mortem): total - attn - prep ~= 63us is FIXED harness overhead
// (insensitive to prep across 4 rewrites); optimize attn only.

#define NQ 32
#define NS 25
#define NL 64
#define NF 256
#define NH 64

#define K2LOG2E 2.8853900817779268f
#define C_LOG2E 1.4426950408889634f

typedef __attribute__((ext_vector_type(8))) short bf16x8;
typedef __attribute__((ext_vector_type(4))) float f32x4;

__device__ inline unsigned short f2bf(float x) {  // RNE
    union { float f; unsigned int u; } v; v.f = x;
    unsigned int r = v.u + 0x7fffu + ((v.u >> 16) & 1u);
    return (unsigned short)(r >> 16);
}

__device__ inline void cvt_hilo(float4 a, float4 b, bf16x8* hi, bf16x8* lo) {
    float x[8] = {a.x, a.y, a.z, a.w, b.x, b.y, b.z, b.w};
    bf16x8 h8, l8;
#pragma unroll
    for (int i = 0; i < 8; ++i) {
        union { float f; unsigned int u; } v; v.f = x[i];
        unsigned short hh = (unsigned short)(v.u >> 16);
        h8[i] = (short)hh;
        union { unsigned int u; float f; } hf; hf.u = (unsigned int)hh << 16;
        union { float f; unsigned int u; } rv; rv.f = x[i] - hf.f;
        l8[i] = (short)(unsigned short)(rv.u >> 16);
    }
    *hi = h8; *lo = l8;
}

// ---------------- prep kernel (unchanged from r5: ~7us, not the bottleneck) ----
#define PROJ_BLOCKS 114
__global__ __launch_bounds__(256) void prep_kernel(
    const float* __restrict__ qs, const float* __restrict__ hs,
    const float* __restrict__ W, const float* __restrict__ b,
    float* __restrict__ Wqs, float* __restrict__ Whs,
    unsigned short* __restrict__ hsT)
{
    __shared__ unsigned short T[64 * 72];
    const int t = threadIdx.x;
    const int bid = blockIdx.x;

    if (bid < PROJ_BLOCKS) {
        const int w = t >> 6, lane = t & 63;
        const int m15 = lane & 15, quad = lane >> 4;
        const int r0 = bid * 32 + (w & 1) * 16;
        const int h0 = (w >> 1) * 32;
        const bool is_q = (r0 < 2048);
        const float* Xrow = is_q ? (qs + (size_t)(r0 + m15) * NF)
                                 : (hs + (size_t)(r0 - 2048 + m15) * NF);
        f32x4 acc[2] = {(f32x4){0.f,0.f,0.f,0.f}, (f32x4){0.f,0.f,0.f,0.f}};

#pragma unroll 2
        for (int kk = 0; kk < 8; ++kk) {
            const int f0 = kk * 32 + quad * 8;
            bf16x8 xhi, xlo;
            cvt_hilo(*(const float4*)(Xrow + f0), *(const float4*)(Xrow + f0 + 4),
                     &xhi, &xlo);
#pragma unroll
            for (int nt = 0; nt < 2; ++nt) {
                const float* Wrow = W + (size_t)(h0 + nt * 16 + m15) * NF + f0;
                bf16x8 whi, wlo;
                cvt_hilo(*(const float4*)(Wrow), *(const float4*)(Wrow + 4),
                         &whi, &wlo);
                acc[nt] = __builtin_amdgcn_mfma_f32_16x16x32_bf16(xhi, whi, acc[nt], 0, 0, 0);
                acc[nt] = __builtin_amdgcn_mfma_f32_16x16x32_bf16(xhi, wlo, acc[nt], 0, 0, 0);
                acc[nt] = __builtin_amdgcn_mfma_f32_16x16x32_bf16(xlo, whi, acc[nt], 0, 0, 0);
            }
        }
#pragma unroll
        for (int nt = 0; nt < 2; ++nt) {
            const int h = h0 + nt * 16 + m15;
            const float bias = b[h];
#pragma unroll
            for (int r = 0; r < 4; ++r) {
                const int row = r0 + quad * 4 + r;
                const float v = acc[nt][r] + bias;
                if (is_q) Wqs[(size_t)row * NH + h] = v * K2LOG2E;
                else      Whs[(size_t)(row - 2048) * NH + h] = v;
            }
        }
    } else {
        const int b2 = bid - PROJ_BLOCKS;
        const int s = b2 >> 2;
        const int f0 = (b2 & 3) * 64;
        const float4* h4p = (const float4*)(hs + (size_t)s * NL * NF);
#pragma unroll
        for (int u = 0; u < 4; ++u) {
            int idx = t + 256 * u;
            int j = idx >> 4, fq = idx & 15;
            float4 v = h4p[j * 64 + (f0 >> 2) + fq];
            T[(4 * fq + 0) * 72 + j] = f2bf(v.x);
            T[(4 * fq + 1) * 72 + j] = f2bf(v.y);
            T[(4 * fq + 2) * 72 + j] = f2bf(v.z);
            T[(4 * fq + 3) * 72 + j] = f2bf(v.w);
        }
        __syncthreads();
#pragma unroll
        for (int u = 0; u < 2; ++u) {
            int idx = t + 256 * u;
            int fl = idx >> 3, jg = idx & 7;
            uint4 v = *(const uint4*)&T[fl * 72 + jg * 8];
            *(uint4*)&hsT[(size_t)(s * 256 + f0 + fl) * 64 + jg * 8] = v;
        }
    }
}

// ---------------- fused attention kernel ----------------
// Grid 3200: (q, s, quarter). Block: 16 i-rows x 64 j. 256 threads.
// LDS: A f32 [16][68] @0 (4352B) | B f32 [64][68] @4352B (17408B) = 21760B -> 7 blk/CU
//      att bf16 [16][72] overlaps A after scores (race-guarded by one barrier).
// Softmax is fully in-wave (rows live in 16 consecutive lanes -> shfl_xor).
#define AS 68
#define B_OFF 1088          // floats (16*68)
#define SMEMF 5440          // 21760 B

__global__ __launch_bounds__(256, 7) void attn_kernel(
    const float* __restrict__ Wqs, const float* __restrict__ Whs,
    const unsigned short* __restrict__ hsT, float* __restrict__ out)
{
    __shared__ float smem[SMEMF];
    const int t = threadIdx.x;
    const int bid = blockIdx.x;
    const int qt = bid & 3;
    const int s = (bid >> 2) % NS;
    const int q = bid / (4 * NS);

    // ---- stage A (16x64) and B (64x64), row-major stride 68 ----
    {
        const float4* a4 = (const float4*)(Wqs + ((size_t)q * NL + qt * 16) * NH);
        const float4* b4 = (const float4*)(Whs + (size_t)s * NL * NH);
        {
            int i = t >> 4, g = t & 15;
            *(float4*)&smem[i * AS + 4 * g] = a4[t];
        }
#pragma unroll
        for (int u = 0; u < 4; ++u) {
            int idx = t + 256 * u;
            int j = idx >> 4, g = idx & 15;
            *(float4*)&smem[B_OFF + j * AS + 4 * g] = b4[idx];
        }
    }
    __syncthreads();

    // ---- scores: row i = t>>4, cols jn+16*jj; quad-combined rcp ----
    const int irow = t >> 4;
    const int jn = t & 15;
    float sum[4] = {0.f, 0.f, 0.f, 0.f};

#pragma unroll 4
    for (int h4 = 0; h4 < 16; ++h4) {
        float4 av = *(const float4*)&smem[irow * AS + 4 * h4];   // broadcast in group
        float4 bv[4];
#pragma unroll
        for (int jj = 0; jj < 4; ++jj)
            bv[jj] = *(const float4*)&smem[B_OFF + (jn + 16 * jj) * AS + 4 * h4];
#pragma unroll
        for (int jj = 0; jj < 4; ++jj) {
            float e0 = __builtin_amdgcn_exp2f(fminf(av.x * bv[jj].x, 18.f));
            float e1 = __builtin_amdgcn_exp2f(fminf(av.y * bv[jj].y, 18.f));
            float e2 = __builtin_amdgcn_exp2f(fminf(av.z * bv[jj].z, 18.f));
            float e3 = __builtin_amdgcn_exp2f(fminf(av.w * bv[jj].w, 18.f));
            float s01 = e0 + e1, s23 = e2 + e3;
            float d01 = fmaf(e0, e1, s01) + 1.f;
            float d23 = fmaf(e2, e3, s23) + 1.f;
            float num = fmaf(s01 + 2.f, d23, (s23 + 2.f) * d01);
            sum[jj] = fmaf(num, __builtin_amdgcn_rcpf(d01 * d23), sum[jj]);
        }
    }
    __syncthreads();  // all A/B reads complete before att overwrites A region

    // ---- in-wave softmax over j (row = 16 consecutive lanes, 4 cols each) ----
    {
        float sc[4];
#pragma unroll
        for (int jj = 0; jj < 4; ++jj) sc[jj] = -2.f * sum[jj];
        float m = fmaxf(fmaxf(sc[0], sc[1]), fmaxf(sc[2], sc[3]));
        m = fmaxf(m, __shfl_xor(m, 1));
        m = fmaxf(m, __shfl_xor(m, 2));
        m = fmaxf(m, __shfl_xor(m, 4));
        m = fmaxf(m, __shfl_xor(m, 8));
        float p[4];
        float d = 0.f;
#pragma unroll
        for (int jj = 0; jj < 4; ++jj) {
            p[jj] = __builtin_amdgcn_exp2f((sc[jj] - m) * C_LOG2E);
            d += p[jj];
        }
        d += __shfl_xor(d, 1);
        d += __shfl_xor(d, 2);
        d += __shfl_xor(d, 4);
        d += __shfl_xor(d, 8);
        const float inv = __builtin_amdgcn_rcpf(d);
        unsigned short* att = (unsigned short*)smem;  // [16][72] bf16 over dead A
#pragma unroll
        for (int jj = 0; jj < 4; ++jj)
            att[irow * 72 + jn + 16 * jj] = f2bf(p[jj] * inv);
    }
    __syncthreads();

    // ---- PV via bf16 MFMA: [16 x 64j] @ [64j x 256f]; wave wv -> f-tiles wv*4.. ----
    const int lane = t & 63;
    const int wv = t >> 6;
    const int m15 = lane & 15;
    const int quad = lane >> 4;

    bf16x8 afr[2];  // A[m=lane&15][k=quad*8+idx], k-chunk k2: j = k2*32 + quad*8..
#pragma unroll
    for (int k = 0; k < 2; ++k)
        afr[k] = *(const bf16x8*)((const char*)smem + m15 * 144 + k * 64 + quad * 16);

    const unsigned short* hsTs = hsT + (size_t)s * NF * NL;
    f32x4 acc[4];
#pragma unroll
    for (int n = 0; n < 4; ++n) acc[n] = (f32x4){0.f, 0.f, 0.f, 0.f};

#pragma unroll
    for (int k = 0; k < 2; ++k) {
        bf16x8 bfr[4];  // B[k][n=lane&15]: hsT row f, 8 consecutive j
#pragma unroll
        for (int n = 0; n < 4; ++n)
            bfr[n] = *(const bf16x8*)(hsTs
                        + (size_t)((wv * 4 + n) * 16 + m15) * 64 + k * 32 + quad * 8);
#pragma unroll
        for (int n = 0; n < 4; ++n)
            acc[n] = __builtin_amdgcn_mfma_f32_16x16x32_bf16(afr[k], bfr[n], acc[n], 0, 0, 0);
    }

    // C layout: col(f) = lane&15, row(i) = quad*4 + reg
    const size_t obase = ((size_t)(q * NS + s) * NL + qt * 16) * NF;
#pragma unroll
    for (int n = 0; n < 4; ++n)
#pragma unroll
        for (int r = 0; r < 4; ++r)
            out[obase + (size_t)(quad * 4 + r) * NF + (wv * 4 + n) * 16 + m15] = acc[n][r];
}

extern "C" void kernel_launch(void* const* d_in, const int* in_sizes, int n_in,
                              void* d_out, int out_size, void* d_ws, size_t ws_size,
                              hipStream_t stream) {
    const float* qs = (const float*)d_in[0];
    const float* hs = (const float*)d_in[1];
    const float* W  = (const float*)d_in[2];
    const float* b  = (const float*)d_in[3];
    float* out = (float*)d_out;

    float* Wqs = (float*)d_ws;                         // 131072 f
    float* Whs = Wqs + NQ * NL * NH;                   // 102400 f
    unsigned short* hsT = (unsigned short*)(Whs + NS * NL * NH);  // 409600 bf16

    prep_kernel<<<PROJ_BLOCKS + NS * 4, 256, 0, stream>>>(qs, hs, W, b, Wqs, Whs, hsT);
    attn_kernel<<<NQ * NS * 4, 256, 0, stream>>>(Wqs, Whs, hsT, out);
}

// Round 7
// 118.744 us; speedup vs baseline: 1.5683x; 1.0064x over previous
//
#include <hip/hip_runtime.h>

// Q=32, S=25, L=64, F=256, H=64
// out[q,s,i,f] = sum_j softmax_j( sum_h tanh(Wq[q,i,h]*Wh[s,j,h]) ) * hs[s,j,f]
// Wq = (qs @ W^T + b) * 2*log2(e)  (pre-scaled: exp2 arg ready), Wh = hs @ W^T + b
// tanh(x) = 1 - 2/(1+exp2(2log2e*x)); per-row constant 64 drops under softmax.
// 4 h-terms share one v_rcp (exp2 arg clamped <= 30: d<=2^61, den<=2^122, safe).
// r6 post-mortem: issue-bound on VALU port -> this round packs mul/clamp into
// v_pk_*_f32 (float2), immediate-offset LDS reads, min-form softmax.
// total - attn - prep ~= 63-70us is FIXED harness overhead; optimize attn only.

#define NQ 32
#define NS 25
#define NL 64
#define NF 256
#define NH 64

#define K2LOG2E 2.8853900817779268f

typedef __attribute__((ext_vector_type(8))) short bf16x8;
typedef __attribute__((ext_vector_type(4))) float f32x4;
typedef __attribute__((ext_vector_type(2))) float v2f;

__device__ inline unsigned short f2bf(float x) {  // RNE
    union { float f; unsigned int u; } v; v.f = x;
    unsigned int r = v.u + 0x7fffu + ((v.u >> 16) & 1u);
    return (unsigned short)(r >> 16);
}

__device__ inline void cvt_hilo(float4 a, float4 b, bf16x8* hi, bf16x8* lo) {
    float x[8] = {a.x, a.y, a.z, a.w, b.x, b.y, b.z, b.w};
    bf16x8 h8, l8;
#pragma unroll
    for (int i = 0; i < 8; ++i) {
        union { float f; unsigned int u; } v; v.f = x[i];
        unsigned short hh = (unsigned short)(v.u >> 16);
        h8[i] = (short)hh;
        union { unsigned int u; float f; } hf; hf.u = (unsigned int)hh << 16;
        union { float f; unsigned int u; } rv; rv.f = x[i] - hf.f;
        l8[i] = (short)(unsigned short)(rv.u >> 16);
    }
    *hi = h8; *lo = l8;
}

// ---------------- prep kernel (unchanged from r5/r6: ~3-7us, not the bottleneck) ----
#define PROJ_BLOCKS 114
__global__ __launch_bounds__(256) void prep_kernel(
    const float* __restrict__ qs, const float* __restrict__ hs,
    const float* __restrict__ W, const float* __restrict__ b,
    float* __restrict__ Wqs, float* __restrict__ Whs,
    unsigned short* __restrict__ hsT)
{
    __shared__ unsigned short T[64 * 72];
    const int t = threadIdx.x;
    const int bid = blockIdx.x;

    if (bid < PROJ_BLOCKS) {
        const int w = t >> 6, lane = t & 63;
        const int m15 = lane & 15, quad = lane >> 4;
        const int r0 = bid * 32 + (w & 1) * 16;
        const int h0 = (w >> 1) * 32;
        const bool is_q = (r0 < 2048);
        const float* Xrow = is_q ? (qs + (size_t)(r0 + m15) * NF)
                                 : (hs + (size_t)(r0 - 2048 + m15) * NF);
        f32x4 acc[2] = {(f32x4){0.f,0.f,0.f,0.f}, (f32x4){0.f,0.f,0.f,0.f}};

#pragma unroll 2
        for (int kk = 0; kk < 8; ++kk) {
            const int f0 = kk * 32 + quad * 8;
            bf16x8 xhi, xlo;
            cvt_hilo(*(const float4*)(Xrow + f0), *(const float4*)(Xrow + f0 + 4),
                     &xhi, &xlo);
#pragma unroll
            for (int nt = 0; nt < 2; ++nt) {
                const float* Wrow = W + (size_t)(h0 + nt * 16 + m15) * NF + f0;
                bf16x8 whi, wlo;
                cvt_hilo(*(const float4*)(Wrow), *(const float4*)(Wrow + 4),
                         &whi, &wlo);
                acc[nt] = __builtin_amdgcn_mfma_f32_16x16x32_bf16(xhi, whi, acc[nt], 0, 0, 0);
                acc[nt] = __builtin_amdgcn_mfma_f32_16x16x32_bf16(xhi, wlo, acc[nt], 0, 0, 0);
                acc[nt] = __builtin_amdgcn_mfma_f32_16x16x32_bf16(xlo, whi, acc[nt], 0, 0, 0);
            }
        }
#pragma unroll
        for (int nt = 0; nt < 2; ++nt) {
            const int h = h0 + nt * 16 + m15;
            const float bias = b[h];
#pragma unroll
            for (int r = 0; r < 4; ++r) {
                const int row = r0 + quad * 4 + r;
                const float v = acc[nt][r] + bias;
                if (is_q) Wqs[(size_t)row * NH + h] = v * K2LOG2E;
                else      Whs[(size_t)(row - 2048) * NH + h] = v;
            }
        }
    } else {
        const int b2 = bid - PROJ_BLOCKS;
        const int s = b2 >> 2;
        const int f0 = (b2 & 3) * 64;
        const float4* h4p = (const float4*)(hs + (size_t)s * NL * NF);
#pragma unroll
        for (int u = 0; u < 4; ++u) {
            int idx = t + 256 * u;
            int j = idx >> 4, fq = idx & 15;
            float4 v = h4p[j * 64 + (f0 >> 2) + fq];
            T[(4 * fq + 0) * 72 + j] = f2bf(v.x);
            T[(4 * fq + 1) * 72 + j] = f2bf(v.y);
            T[(4 * fq + 2) * 72 + j] = f2bf(v.z);
            T[(4 * fq + 3) * 72 + j] = f2bf(v.w);
        }
        __syncthreads();
#pragma unroll
        for (int u = 0; u < 2; ++u) {
            int idx = t + 256 * u;
            int fl = idx >> 3, jg = idx & 7;
            uint4 v = *(const uint4*)&T[fl * 72 + jg * 8];
            *(uint4*)&hsT[(size_t)(s * 256 + f0 + fl) * 64 + jg * 8] = v;
        }
    }
}

// ---------------- fused attention kernel ----------------
// Grid 3200: (q, s, quarter). Block: 16 i-rows x 64 j. 256 threads.
// LDS: A f32 [16][68] @0 (4352B) | B f32 [64][68] @4352B (17408B) = 21760B -> 7 blk/CU
//      att bf16 [16][72] overlaps A after scores (barrier-guarded).
#define AS 68
#define B_OFF 1088          // floats (16*68)
#define SMEMF 5440          // 21760 B

__global__ __launch_bounds__(256, 7) void attn_kernel(
    const float* __restrict__ Wqs, const float* __restrict__ Whs,
    const unsigned short* __restrict__ hsT, float* __restrict__ out)
{
    __shared__ float smem[SMEMF];
    const int t = threadIdx.x;
    const int bid = blockIdx.x;
    const int qt = bid & 3;
    const int s = (bid >> 2) % NS;
    const int q = bid / (4 * NS);

    // ---- stage A (16x64) and B (64x64), row-major stride 68 ----
    {
        const float4* a4 = (const float4*)(Wqs + ((size_t)q * NL + qt * 16) * NH);
        const float4* b4 = (const float4*)(Whs + (size_t)s * NL * NH);
        {
            int i = t >> 4, g = t & 15;
            *(float4*)&smem[i * AS + 4 * g] = a4[t];
        }
#pragma unroll
        for (int u = 0; u < 4; ++u) {
            int idx = t + 256 * u;
            int j = idx >> 4, g = idx & 15;
            *(float4*)&smem[B_OFF + j * AS + 4 * g] = b4[idx];
        }
    }
    __syncthreads();

    // ---- scores: row i = t>>4, cols jn+16*jj; pk mul/clamp + quad-combined rcp ----
    const int irow = t >> 4;
    const int jn = t & 15;
    float sum[4] = {0.f, 0.f, 0.f, 0.f};
    {
        const float* Ab = &smem[irow * AS];
        const float* Bb[4];
#pragma unroll
        for (int jj = 0; jj < 4; ++jj) Bb[jj] = &smem[B_OFF + (jn + 16 * jj) * AS];
        const v2f vcl = {30.f, 30.f};

#pragma unroll 4
        for (int h4 = 0; h4 < 16; ++h4) {
            float4 av = *(const float4*)(Ab + 4 * h4);
            v2f alo = {av.x, av.y}, ahi = {av.z, av.w};
#pragma unroll
            for (int jj = 0; jj < 4; ++jj) {
                float4 bv = *(const float4*)(Bb[jj] + 4 * h4);
                v2f blo = {bv.x, bv.y}, bhi = {bv.z, bv.w};
                v2f xlo = __builtin_elementwise_min(alo * blo, vcl);  // v_pk_mul/min
                v2f xhi = __builtin_elementwise_min(ahi * bhi, vcl);
                float e0 = __builtin_amdgcn_exp2f(xlo[0]);
                float e1 = __builtin_amdgcn_exp2f(xlo[1]);
                float e2 = __builtin_amdgcn_exp2f(xhi[0]);
                float e3 = __builtin_amdgcn_exp2f(xhi[1]);
                float s01 = e0 + e1, s23 = e2 + e3;
                float d01 = fmaf(e0, e1, s01) + 1.f;
                float d23 = fmaf(e2, e3, s23) + 1.f;
                float num = fmaf(s01 + 2.f, d23, (s23 + 2.f) * d01);
                sum[jj] = fmaf(num, __builtin_amdgcn_rcpf(d01 * d23), sum[jj]);
            }
        }
    }
    __syncthreads();  // all A/B reads complete before att overwrites A region

    // ---- in-wave softmax over j (min-form: score = -2*sum + const) ----
    {
        float mn = fminf(fminf(sum[0], sum[1]), fminf(sum[2], sum[3]));
        mn = fminf(mn, __shfl_xor(mn, 1));
        mn = fminf(mn, __shfl_xor(mn, 2));
        mn = fminf(mn, __shfl_xor(mn, 4));
        mn = fminf(mn, __shfl_xor(mn, 8));
        float p[4];
        float d = 0.f;
#pragma unroll
        for (int jj = 0; jj < 4; ++jj) {
            p[jj] = __builtin_amdgcn_exp2f((mn - sum[jj]) * K2LOG2E);
            d += p[jj];
        }
        d += __shfl_xor(d, 1);
        d += __shfl_xor(d, 2);
        d += __shfl_xor(d, 4);
        d += __shfl_xor(d, 8);
        const float inv = __builtin_amdgcn_rcpf(d);
        unsigned short* att = (unsigned short*)smem;  // [16][72] bf16 over dead A
#pragma unroll
        for (int jj = 0; jj < 4; ++jj)
            att[irow * 72 + jn + 16 * jj] = f2bf(p[jj] * inv);
    }
    __syncthreads();

    // ---- PV via bf16 MFMA: [16 x 64j] @ [64j x 256f]; wave wv -> f-tiles wv*4.. ----
    const int lane = t & 63;
    const int wv = t >> 6;
    const int m15 = lane & 15;
    const int quad = lane >> 4;

    bf16x8 afr[2];  // A[m=lane&15][k=quad*8+idx]
#pragma unroll
    for (int k = 0; k < 2; ++k)
        afr[k] = *(const bf16x8*)((const char*)smem + m15 * 144 + k * 64 + quad * 16);

    const unsigned short* hsTs = hsT + (size_t)s * NF * NL;
    f32x4 acc[4];
#pragma unroll
    for (int n = 0; n < 4; ++n) acc[n] = (f32x4){0.f, 0.f, 0.f, 0.f};

#pragma unroll
    for (int k = 0; k < 2; ++k) {
        bf16x8 bfr[4];  // B[k][n=lane&15]: hsT row f, 8 consecutive j
#pragma unroll
        for (int n = 0; n < 4; ++n)
            bfr[n] = *(const bf16x8*)(hsTs
                        + (size_t)((wv * 4 + n) * 16 + m15) * 64 + k * 32 + quad * 8);
#pragma unroll
        for (int n = 0; n < 4; ++n)
            acc[n] = __builtin_amdgcn_mfma_f32_16x16x32_bf16(afr[k], bfr[n], acc[n], 0, 0, 0);
    }

    // C layout: col(f) = lane&15, row(i) = quad*4 + reg
    const size_t obase = ((size_t)(q * NS + s) * NL + qt * 16) * NF;
#pragma unroll
    for (int n = 0; n < 4; ++n)
#pragma unroll
        for (int r = 0; r < 4; ++r)
            out[obase + (size_t)(quad * 4 + r) * NF + (wv * 4 + n) * 16 + m15] = acc[n][r];
}

extern "C" void kernel_launch(void* const* d_in, const int* in_sizes, int n_in,
                              void* d_out, int out_size, void* d_ws, size_t ws_size,
                              hipStream_t stream) {
    const float* qs = (const float*)d_in[0];
    const float* hs = (const float*)d_in[1];
    const float* W  = (const float*)d_in[2];
    const float* b  = (const float*)d_in[3];
    float* out = (float*)d_out;

    float* Wqs = (float*)d_ws;                         // 131072 f
    float* Whs = Wqs + NQ * NL * NH;                   // 102400 f
    unsigned short* hsT = (unsigned short*)(Whs + NS * NL * NH);  // 409600 bf16

    prep_kernel<<<PROJ_BLOCKS + NS * 4, 256, 0, stream>>>(qs, hs, W, b, Wqs, Whs, hsT);
    attn_kernel<<<NQ * NS * 4, 256, 0, stream>>>(Wqs, Whs, hsT, out);
}